// Round 5
// baseline (248.408 us; speedup 1.0000x reference)
//
#include <hip/hip_runtime.h>
#include <math.h>

// v13: v10 skeleton (121us verified) + two bounded changes:
//   (1) gid fold: G = A*A^T + I via MFMA C-operand identity fragment
//       (index algebra verified against v10's explicit fixup; passed in
//       v11/v12). Removes 32 cmp/select/add per eval + 32 zero-inits.
//   (2) packed-pair GJ solve, SSA-SAFE: plain f32x2 P[9] arrays, all
//       indices compile-time constants, NO union (v12's uR union defeated
//       SROA -> scratch, +77us -- same pathology as v8), NO inline asm
//       (v11's fmac_dpp asm was opaque to the hazard recognizer, +64us).
//       Compiler may emit v_pk_fma_f32 (saves 136 FMA issues/thread/eval);
//       worst case decomposes to v10's scalar form.
// Everything else byte-identical to v10 (passing, absmax 0.0156).

typedef _Float16 f16;
typedef _Float16 f16x2 __attribute__((ext_vector_type(2)));
typedef _Float16 f16x4 __attribute__((ext_vector_type(4)));
typedef _Float16 f16x8 __attribute__((ext_vector_type(8)));
typedef __fp16 h16x2 __attribute__((ext_vector_type(2)));   // builtin return type
typedef float f32x2 __attribute__((ext_vector_type(2)));
typedef float f32x4 __attribute__((ext_vector_type(4)));
typedef float f32x16 __attribute__((ext_vector_type(16)));

#define SAG_P 392   // f16 point stride; row stride 24, aug col at 16
#define SZ_P  36    // f32
#define SH_P  72    // f16
#define SW_P  20    // f32
#define SWP_C 20    // f32 stride of sWp per (wave,point)

__device__ __forceinline__ float fastTanh(float x) {
    float e = exp2f(x * 2.885390081777927f);
    return 1.0f - 2.0f * __builtin_amdgcn_rcpf(1.0f + e);
}

__device__ __forceinline__ f16x2 pk2(float a, float b) {
    h16x2 p = __builtin_amdgcn_cvt_pkrtz(a, b);
    return __builtin_bit_cast(f16x2, p);
}

typedef union { f16x4 v4; f16x2 v2[2]; } u16x4;
typedef union { f16x8 v8; f16x2 v2[4]; int i32[4]; } u16x8;

// broadcast lane K of each 16-lane row via DPP row_newbcast (VALU, no DS)
template<int K>
__device__ __forceinline__ float bcf(float x) {
    int v = __builtin_amdgcn_mov_dpp(__builtin_bit_cast(int, x),
                                     0x150 | K, 0xf, 0xf, false);
    return __builtin_bit_cast(float, v);
}

// Paired Gauss-Jordan, two independent systems, rows as f32x2 pairs.
// P[0..7] = G row cols 0..15, P[8][0] = aug, P[8][1] = pad.
// All array indices are compile-time constants -> full SROA to registers.
template<int K>
__device__ __forceinline__ void fe2p(f32x2 (&P0)[9], f32x2 (&P1)[9],
                                     const int i16, float &inv0, float &inv1) {
    if constexpr (K < 16) {
        constexpr int mK = K >> 1, eK = K & 1;
        float p0  = bcf<K>(P0[mK][eK]);
        float p1  = bcf<K>(P1[mK][eK]);
        float pi0 = __builtin_amdgcn_rcpf(p0);
        float pi1 = __builtin_amdgcn_rcpf(p1);
        if (i16 == K) { inv0 = pi0; inv1 = pi1; }
        float nf0 = (i16 == K) ? 0.0f : -(P0[mK][eK] * pi0);
        float nf1 = (i16 == K) ? 0.0f : -(P1[mK][eK] * pi1);
        f32x2 n0 = {nf0, nf0};
        f32x2 n1 = {nf1, nf1};
        // pairs from (K+1)>>1: for even K this redundantly updates pivot
        // col K (residual ~2^-23 * old value, never read again) -- keeps
        // updates pair-aligned. Verified numerically identical in v12.
        #pragma unroll
        for (int m = (K + 1) >> 1; m < 9; ++m) {
            f32x2 b0, b1;
            b0[0] = bcf<K>(P0[m][0]); b0[1] = bcf<K>(P0[m][1]);
            b1[0] = bcf<K>(P1[m][0]); b1[1] = bcf<K>(P1[m][1]);
            P0[m] += n0 * b0;
            P1[m] += n1 * b1;
        }
        fe2p<K + 1>(P0, P1, i16, inv0, inv1);
    }
}

__global__ __launch_bounds__(256, 1)
void geo_kernel(const float* __restrict__ zin, const float* __restrict__ tg,
                const float* __restrict__ W1g, const float* __restrict__ b1g,
                const float* __restrict__ W2g, const float* __restrict__ b2g,
                const int* __restrict__ nsg, float* __restrict__ outg, int B)
{
    __shared__ __align__(16) f16   sAG[2][16 * SAG_P];      // A, then G (+aug)
    __shared__ __align__(16) f16   sHT[2][16 * SH_P];       // h, later t
    __shared__ __align__(16) float sZI[2][16 * SZ_P];
    __shared__ __align__(16) float sKV[2][16 * SW_P];
    __shared__ __align__(16) float sWp[2][4 * 16 * SWP_C];  // w partials per wave

    const int tid = threadIdx.x;
    const int w = tid >> 6;
    const int l = tid & 63;
    const int i16 = l & 15, q4 = l >> 4, h2 = l >> 5, sc = q4 & 1;

    // ---------------- hoisted weight fragments (quarter per wave) ----------
    f16x8 w2a[4][2];   // A-stage A-op: W2^T[e=i16+16(4w+t)][k=8q4+j+32ch]
    #pragma unroll
    for (int t = 0; t < 4; ++t)
        #pragma unroll
        for (int ch = 0; ch < 2; ++ch)
            #pragma unroll
            for (int j = 0; j < 8; ++j)
                w2a[t][ch][j] = (f16)W2g[(8*q4 + j + 32*ch)*256 + i16 + 16*(4*w + t)];

    f16x8 w2r[8];      // r-stage A-op: W2[n=i16+16w][e=8q4+j+32ch]
    #pragma unroll
    for (int ch = 0; ch < 8; ++ch)
        #pragma unroll
        for (int j = 0; j < 8; ++j)
            w2r[ch][j] = (f16)W2g[(i16 + 16*w)*256 + 8*q4 + j + 32*ch];

    f16x8 w1h;         // H-stage A-op: W1^T[n=i16+16w][x=8q4+j], zero-pad k>=16
    #pragma unroll
    for (int j = 0; j < 8; ++j) {
        int k = 8*q4 + j;
        w1h[j] = (k < 16) ? (f16)W1g[k*64 + i16 + 16*w] : (f16)0.0f;
    }

    f16x8 w1q[2];      // q-stage A-op: W1[i=i16][n=8q4+j+32ch]
    #pragma unroll
    for (int ch = 0; ch < 2; ++ch)
        #pragma unroll
        for (int j = 0; j < 8; ++j)
            w1q[ch][j] = (f16)W1g[i16*64 + 8*q4 + j + 32*ch];

    float b2v[4][4];   // b2[e = 16*(4w+t) + 4q4+reg]
    #pragma unroll
    for (int t = 0; t < 4; ++t)
        #pragma unroll
        for (int reg = 0; reg < 4; ++reg)
            b2v[t][reg] = b2g[16*(4*w + t) + 4*q4 + reg];
    float b1v[4];      // b1[n = 16w + 4q4+reg]
    #pragma unroll
    for (int reg = 0; reg < 4; ++reg) b1v[reg] = b1g[16*w + 4*q4 + reg];

    // identity C-in fragment for AAT: 32x32 C/D layout is
    // row = (reg&3) + 8*(reg>>2) + 4*(lane>>5), col = lane&31.
    f32x16 gid;
    #pragma unroll
    for (int reg = 0; reg < 16; ++reg) {
        int row = (reg & 3) + 8*(reg >> 2) + 4*h2;
        gid[reg] = (row == (l & 31)) ? 1.0f : 0.0f;
    }

    // ---------------- RK4 state: thread owns points (g,tid>>4) ------------
    const int pb = blockIdx.x * 32;
    const int p_cmb = tid >> 4;            // == 4w + q4
    const int g16 = tid & 15;
    f32x2 zc[2], ar[2];
    #pragma unroll
    for (int g = 0; g < 2; ++g) {
        int pl = pb + 16*g + p_cmb;
        int pg = (pl < B) ? pl : (B - 1);
        zc[g] = *(const f32x2*)&zin[pg*32 + 2*g16];
        *(f32x2*)&sZI[g][p_cmb*SZ_P + 2*g16] = zc[g];
    }
    __syncthreads();

    const float tv = tg[0];
    const int nst = nsg[0];
    const float dt = tv / (float)nst;

    const int xmask = (q4 >= 2) ? 0 : -1;

    #pragma unroll 1
    for (int st = 0; st < nst; ++st) {
        #pragma unroll 1
        for (int s = 0; s < 4; ++s) {
            float dreg[2][4];
            // ======== X-load + H, both sets ========
            #pragma unroll
            for (int g = 0; g < 2; ++g) {
                u16x8 xf;
                {
                    f32x4 xa = *(const f32x4*)&sZI[g][i16*SZ_P + 8*sc];
                    f32x4 xb = *(const f32x4*)&sZI[g][i16*SZ_P + 8*sc + 4];
                    xf.v2[0] = pk2(xa[0], xa[1]);
                    xf.v2[1] = pk2(xa[2], xa[3]);
                    xf.v2[2] = pk2(xb[0], xb[1]);
                    xf.v2[3] = pk2(xb[2], xb[3]);
                    #pragma unroll
                    for (int jp = 0; jp < 4; ++jp) xf.i32[jp] &= xmask;
                }
                f32x4 hc = {0.f, 0.f, 0.f, 0.f};
                hc = __builtin_amdgcn_mfma_f32_16x16x32_f16(w1h, xf.v8, hc, 0, 0, 0);
                float hv[4];
                #pragma unroll
                for (int reg = 0; reg < 4; ++reg) {
                    hv[reg] = fastTanh(hc[reg] + b1v[reg]);
                    dreg[g][reg] = hv[reg]*hv[reg] - 1.0f;
                }
                u16x4 hv4;
                hv4.v2[0] = pk2(hv[0], hv[1]);
                hv4.v2[1] = pk2(hv[2], hv[3]);
                *(f16x4*)&sHT[g][i16*SH_P + 16*w + 4*q4] = hv4.v4;
            }
            __syncthreads();   // B1: h ready
            // ======== A stage, both sets ========
            #pragma unroll
            for (int g = 0; g < 2; ++g) {
                f32x4 vA = *(const f32x4*)&sZI[g][i16*SZ_P + 16 + 4*w];
                f16x8 hf0 = *(const f16x8*)&sHT[g][i16*SH_P + 8*q4];
                f16x8 hf1 = *(const f16x8*)&sHT[g][i16*SH_P + 8*q4 + 32];
                float pw[4] = {0.f, 0.f, 0.f, 0.f};
                #pragma unroll
                for (int t = 0; t < 4; ++t) {
                    f32x4 ac = {0.f, 0.f, 0.f, 0.f};
                    ac = __builtin_amdgcn_mfma_f32_16x16x32_f16(w2a[t][0], hf0, ac, 0, 0, 0);
                    ac = __builtin_amdgcn_mfma_f32_16x16x32_f16(w2a[t][1], hf1, ac, 0, 0, 0);
                    float a0 = ac[0] + b2v[t][0], a1 = ac[1] + b2v[t][1];
                    float a2 = ac[2] + b2v[t][2], a3 = ac[3] + b2v[t][3];
                    float vv = vA[t];
                    pw[0] += vv * a0; pw[1] += vv * a1;
                    pw[2] += vv * a2; pw[3] += vv * a3;
                    u16x4 av;
                    av.v2[0] = pk2(a0, a1);
                    av.v2[1] = pk2(a2, a3);
                    *(f16x4*)&sAG[g][i16*SAG_P + 24*(4*w + t) + 4*q4] = av.v4;
                }
                f32x4 pwv = {pw[0], pw[1], pw[2], pw[3]};
                *(f32x4*)&sWp[g][(w*16 + i16)*SWP_C + 4*q4] = pwv;
            }
            __syncthreads();   // B2: A + w partials ready
            // ======== AAT (2 pair-MFMAs/wave/set) -> G^T over A region ========
            // identity folded into C-in (gid); no post-add fixup needed
            #pragma unroll
            for (int g = 0; g < 2; ++g) {
                #pragma unroll
                for (int u0 = 0; u0 < 2; ++u0) {
                    int u = 2*w + u0;
                    int pt = 2*u + sc;
                    f16x8 af = *(const f16x8*)&sAG[g][pt*SAG_P + 24*i16 + 8*h2];
                    f32x16 gacc = __builtin_amdgcn_mfma_f32_32x32x16_f16(af, af, gid, 0, 0, 0);
                    float gv[8];
                    #pragma unroll
                    for (int rr = 0; rr < 4; ++rr) {
                        gv[rr]     = sc ? gacc[rr + 8]  : gacc[rr];
                        gv[4 + rr] = sc ? gacc[rr + 12] : gacc[rr + 4];
                    }
                    u16x4 g0p, g1p;
                    g0p.v2[0] = pk2(gv[0], gv[1]); g0p.v2[1] = pk2(gv[2], gv[3]);
                    g1p.v2[0] = pk2(gv[4], gv[5]); g1p.v2[1] = pk2(gv[6], gv[7]);
                    *(f16x4*)&sAG[g][pt*SAG_P + 24*i16 + 4*h2]     = g0p.v4;
                    *(f16x4*)&sAG[g][pt*SAG_P + 24*i16 + 8 + 4*h2] = g1p.v4;
                }
            }
            // ======== r stage, both sets ========
            #pragma unroll
            for (int g = 0; g < 2; ++g) {
                float vch[8];
                {
                    const float* vp = &sZI[g][i16*SZ_P + 16 + (q4 >> 1)];
                    #pragma unroll
                    for (int c = 0; c < 8; ++c) vch[c] = vp[2*c];
                }
                float wv[8];
                {
                    f32x4 s0 = *(const f32x4*)&sWp[g][(0*16 + i16)*SWP_C + 8*sc];
                    f32x4 s1 = *(const f32x4*)&sWp[g][(1*16 + i16)*SWP_C + 8*sc];
                    f32x4 s2 = *(const f32x4*)&sWp[g][(2*16 + i16)*SWP_C + 8*sc];
                    f32x4 s3 = *(const f32x4*)&sWp[g][(3*16 + i16)*SWP_C + 8*sc];
                    f32x4 t0 = *(const f32x4*)&sWp[g][(0*16 + i16)*SWP_C + 8*sc + 4];
                    f32x4 t1 = *(const f32x4*)&sWp[g][(1*16 + i16)*SWP_C + 8*sc + 4];
                    f32x4 t2 = *(const f32x4*)&sWp[g][(2*16 + i16)*SWP_C + 8*sc + 4];
                    f32x4 t3 = *(const f32x4*)&sWp[g][(3*16 + i16)*SWP_C + 8*sc + 4];
                    #pragma unroll
                    for (int j = 0; j < 4; ++j) {
                        wv[j]     = s0[j] + s1[j] + s2[j] + s3[j];
                        wv[4 + j] = t0[j] + t1[j] + t2[j] + t3[j];
                    }
                }
                f16x2 wfp[4];
                #pragma unroll
                for (int jp = 0; jp < 4; ++jp) wfp[jp] = pk2(wv[2*jp], wv[2*jp + 1]);
                f32x4 racc = {0.f, 0.f, 0.f, 0.f};
                #pragma unroll
                for (int ch = 0; ch < 8; ++ch) {
                    f16 vvh = (f16)vch[ch];
                    f16x2 vv2; vv2.x = vvh; vv2.y = vvh;
                    u16x8 uf;
                    #pragma unroll
                    for (int jp = 0; jp < 4; ++jp) uf.v2[jp] = vv2 * wfp[jp];
                    racc = __builtin_amdgcn_mfma_f32_16x16x32_f16(w2r[ch], uf.v8, racc, 0, 0, 0);
                }
                u16x4 tv4;
                tv4.v2[0] = pk2(dreg[g][0]*racc[0], dreg[g][1]*racc[1]);
                tv4.v2[1] = pk2(dreg[g][2]*racc[2], dreg[g][3]*racc[3]);
                *(f16x4*)&sHT[g][i16*SH_P + 16*w + 4*q4] = tv4.v4;   // t overwrites h
            }
            __syncthreads();   // B4: t ready (G/aug wave-private from here)
            // ======== q stage, both sets ========
            #pragma unroll
            for (int g = 0; g < 2; ++g) {
                int ptq = 4*w + (i16 & 3);
                f16x8 tb0 = *(const f16x8*)&sHT[g][ptq*SH_P + 8*q4];
                f16x8 tb1 = *(const f16x8*)&sHT[g][ptq*SH_P + 8*q4 + 32];
                f32x4 qa = {0.f, 0.f, 0.f, 0.f};
                qa = __builtin_amdgcn_mfma_f32_16x16x32_f16(w1q[0], tb0, qa, 0, 0, 0);
                qa = __builtin_amdgcn_mfma_f32_16x16x32_f16(w1q[1], tb1, qa, 0, 0, 0);
                if (i16 < 4) {
                    #pragma unroll
                    for (int reg = 0; reg < 4; ++reg)
                        sAG[g][(4*w + i16)*SAG_P + 24*(4*q4 + reg) + 16] = (f16)qa[reg];
                }
            }
            // ======== solve G y = aug; paired across sets, packed SSA rows ===
            {
                const int psl = 4*w + q4;
                f32x2 P0[9], P1[9];
                {
                    const f16* rp0 = &sAG[0][psl*SAG_P + 24*i16];
                    const f16* rp1 = &sAG[1][psl*SAG_P + 24*i16];
                    f16x8 ra0 = *(const f16x8*)&rp0[0];
                    f16x8 rb0 = *(const f16x8*)&rp0[8];
                    f16x8 ra1 = *(const f16x8*)&rp1[0];
                    f16x8 rb1 = *(const f16x8*)&rp1[8];
                    #pragma unroll
                    for (int m = 0; m < 4; ++m) {
                        P0[m][0]   = (float)ra0[2*m]; P0[m][1]   = (float)ra0[2*m+1];
                        P0[4+m][0] = (float)rb0[2*m]; P0[4+m][1] = (float)rb0[2*m+1];
                        P1[m][0]   = (float)ra1[2*m]; P1[m][1]   = (float)ra1[2*m+1];
                        P1[4+m][0] = (float)rb1[2*m]; P1[4+m][1] = (float)rb1[2*m+1];
                    }
                    P0[8][0] = (float)rp0[16]; P0[8][1] = 0.0f;
                    P1[8][0] = (float)rp1[16]; P1[8][1] = 0.0f;
                }
                float inv0 = 1.0f, inv1 = 1.0f;
                fe2p<0>(P0, P1, i16, inv0, inv1);
                sKV[0][psl*SW_P + i16] = P0[8][0] * inv0;
                sKV[1][psl*SW_P + i16] = P1[8][0] * inv1;
            }
            // (no barrier: combine reads only this wave's points; DS in-order)
            // ======== RK4 combine, both sets ========
            #pragma unroll
            for (int g = 0; g < 2; ++g) {
                f32x2 kk;
                if (g16 < 8) kk = *(const f32x2*)&sZI[g][p_cmb*SZ_P + 16 + 2*g16];
                else         kk = *(const f32x2*)&sKV[g][p_cmb*SW_P + 2*(g16 - 8)];
                if (s == 0) ar[g] = kk;
                else {
                    float wgt = (s == 3) ? 1.0f : 2.0f;
                    ar[g].x += wgt * kk.x; ar[g].y += wgt * kk.y;
                }
                f32x2 zi;
                if (s < 3) {
                    float alpha = (s < 2) ? (0.5f * dt) : dt;
                    zi.x = zc[g].x + alpha * kk.x; zi.y = zc[g].y + alpha * kk.y;
                } else {
                    float c6 = dt / 6.0f;
                    zc[g].x += c6 * ar[g].x; zc[g].y += c6 * ar[g].y;
                    zi = zc[g];
                }
                *(f32x2*)&sZI[g][p_cmb*SZ_P + 2*g16] = zi;
            }
            __syncthreads();   // B6: zI ready for next eval
        }
    }
    #pragma unroll
    for (int g = 0; g < 2; ++g) {
        int pl = pb + 16*g + p_cmb;
        if (pl < B)
            *(f32x2*)&outg[pl*32 + 2*g16] = zc[g];
    }
}

extern "C" void kernel_launch(void* const* d_in, const int* in_sizes, int n_in,
                              void* d_out, int out_size, void* d_ws, size_t ws_size,
                              hipStream_t stream) {
    (void)n_in; (void)d_ws; (void)ws_size; (void)out_size;
    const float* z  = (const float*)d_in[0];
    const float* t  = (const float*)d_in[1];
    const float* W1 = (const float*)d_in[2];
    const float* b1 = (const float*)d_in[3];
    const float* W2 = (const float*)d_in[4];
    const float* b2 = (const float*)d_in[5];
    const int*   ns = (const int*)d_in[6];
    float* out = (float*)d_out;
    const int B = in_sizes[0] / 32;
    int grid = (B + 31) / 32;
    hipLaunchKernelGGL(geo_kernel, dim3(grid), dim3(256), 0, stream,
                       z, t, W1, b1, W2, b2, ns, out, B);
}

// Round 6
// 162.135 us; speedup vs baseline: 1.5321x; 1.5321x over previous
//
#include <hip/hip_runtime.h>
#include <math.h>

// v14: byte-exact v10 (121us rocprof, verified best) + ONE change:
// s_setprio(1) around the GJ solve. Rationale: v11-v13 post-mortem assigned
// the +64us poison to the gid MFMA C-operand (live-tuple C-in forces per-MFMA
// 16-reg copy + VALU->MFMA SrcC hazard; VGPR evidence 116/116/120 ~ v10+16
// discriminates vs the scratch story), and showed v10's solve is already
// auto-fused v_fmac_f32_dpp (VOP2+DPP combinable; VOP3P pk_fma is not) --
// so solve/AAT are at their floors. Remaining lever: issue arbitration.
// The 2 blocks/CU are barrier-desynced; during a block's solve its waves are
// latency-chain-bound and compete for VALU issue with the other block's
// slack-rich throughput VALU (MFMA pipe is separate). Raising priority for
// the chain phase is the attn-like desync regime where setprio measured
// +4-7%. Everything else identical to v10 (passing, absmax 0.0156).

typedef _Float16 f16;
typedef _Float16 f16x2 __attribute__((ext_vector_type(2)));
typedef _Float16 f16x4 __attribute__((ext_vector_type(4)));
typedef _Float16 f16x8 __attribute__((ext_vector_type(8)));
typedef __fp16 h16x2 __attribute__((ext_vector_type(2)));   // builtin return type
typedef float f32x2 __attribute__((ext_vector_type(2)));
typedef float f32x4 __attribute__((ext_vector_type(4)));
typedef float f32x16 __attribute__((ext_vector_type(16)));

#define SAG_P 392   // f16 point stride; row stride 24, aug col at 16
#define SZ_P  36    // f32
#define SH_P  72    // f16
#define SW_P  20    // f32
#define SWP_C 20    // f32 stride of sWp per (wave,point)

__device__ __forceinline__ float fastTanh(float x) {
    float e = exp2f(x * 2.885390081777927f);
    return 1.0f - 2.0f * __builtin_amdgcn_rcpf(1.0f + e);
}

__device__ __forceinline__ f16x2 pk2(float a, float b) {
    h16x2 p = __builtin_amdgcn_cvt_pkrtz(a, b);
    return __builtin_bit_cast(f16x2, p);
}

typedef union { f16x4 v4; f16x2 v2[2]; } u16x4;
typedef union { f16x8 v8; f16x2 v2[4]; int i32[4]; } u16x8;

// broadcast lane K of each 16-lane row via DPP row_newbcast (VALU, no DS)
template<int K>
__device__ __forceinline__ float bcf(float x) {
    int v = __builtin_amdgcn_mov_dpp(__builtin_bit_cast(int, x),
                                     0x150 | K, 0xf, 0xf, false);
    return __builtin_bit_cast(float, v);
}

// Paired Gauss-Jordan elimination: two independent systems interleaved at
// source level so their serial bcast->rcp->mul->fma chains overlap.
// (compiler auto-fuses mov_dpp + fmac into v_fmac_f32_dpp -- keep VOP2 form)
template<int K>
__device__ __forceinline__ void fe_all2(float (&R0)[17], float (&R1)[17],
                                        const int i16, float &inv0, float &inv1) {
    if constexpr (K < 16) {
        float p0 = bcf<K>(R0[K]);
        float p1 = bcf<K>(R1[K]);
        float pi0 = __builtin_amdgcn_rcpf(p0);
        float pi1 = __builtin_amdgcn_rcpf(p1);
        if (i16 == K) { inv0 = pi0; inv1 = pi1; }
        float f0 = (i16 == K) ? 0.0f : R0[K] * pi0;
        float f1 = (i16 == K) ? 0.0f : R1[K] * pi1;
        #pragma unroll
        for (int j = K + 1; j <= 16; ++j) {
            float v0 = bcf<K>(R0[j]);
            float v1 = bcf<K>(R1[j]);
            R0[j] -= f0 * v0;
            R1[j] -= f1 * v1;
        }
        fe_all2<K + 1>(R0, R1, i16, inv0, inv1);
    }
}

__global__ __launch_bounds__(256, 1)
void geo_kernel(const float* __restrict__ zin, const float* __restrict__ tg,
                const float* __restrict__ W1g, const float* __restrict__ b1g,
                const float* __restrict__ W2g, const float* __restrict__ b2g,
                const int* __restrict__ nsg, float* __restrict__ outg, int B)
{
    __shared__ __align__(16) f16   sAG[2][16 * SAG_P];      // A, then G (+aug)
    __shared__ __align__(16) f16   sHT[2][16 * SH_P];       // h, later t
    __shared__ __align__(16) float sZI[2][16 * SZ_P];
    __shared__ __align__(16) float sKV[2][16 * SW_P];
    __shared__ __align__(16) float sWp[2][4 * 16 * SWP_C];  // w partials per wave

    const int tid = threadIdx.x;
    const int w = tid >> 6;
    const int l = tid & 63;
    const int i16 = l & 15, q4 = l >> 4, h2 = l >> 5, sc = q4 & 1;

    // ---------------- hoisted weight fragments (quarter per wave) ----------
    f16x8 w2a[4][2];   // A-stage A-op: W2^T[e=i16+16(4w+t)][k=8q4+j+32ch]
    #pragma unroll
    for (int t = 0; t < 4; ++t)
        #pragma unroll
        for (int ch = 0; ch < 2; ++ch)
            #pragma unroll
            for (int j = 0; j < 8; ++j)
                w2a[t][ch][j] = (f16)W2g[(8*q4 + j + 32*ch)*256 + i16 + 16*(4*w + t)];

    f16x8 w2r[8];      // r-stage A-op: W2[n=i16+16w][e=8q4+j+32ch]
    #pragma unroll
    for (int ch = 0; ch < 8; ++ch)
        #pragma unroll
        for (int j = 0; j < 8; ++j)
            w2r[ch][j] = (f16)W2g[(i16 + 16*w)*256 + 8*q4 + j + 32*ch];

    f16x8 w1h;         // H-stage A-op: W1^T[n=i16+16w][x=8q4+j], zero-pad k>=16
    #pragma unroll
    for (int j = 0; j < 8; ++j) {
        int k = 8*q4 + j;
        w1h[j] = (k < 16) ? (f16)W1g[k*64 + i16 + 16*w] : (f16)0.0f;
    }

    f16x8 w1q[2];      // q-stage A-op: W1[i=i16][n=8q4+j+32ch]
    #pragma unroll
    for (int ch = 0; ch < 2; ++ch)
        #pragma unroll
        for (int j = 0; j < 8; ++j)
            w1q[ch][j] = (f16)W1g[i16*64 + 8*q4 + j + 32*ch];

    float b2v[4][4];   // b2[e = 16*(4w+t) + 4q4+reg]
    #pragma unroll
    for (int t = 0; t < 4; ++t)
        #pragma unroll
        for (int reg = 0; reg < 4; ++reg)
            b2v[t][reg] = b2g[16*(4*w + t) + 4*q4 + reg];
    float b1v[4];      // b1[n = 16w + 4q4+reg]
    #pragma unroll
    for (int reg = 0; reg < 4; ++reg) b1v[reg] = b1g[16*w + 4*q4 + reg];

    // ---------------- RK4 state: thread owns points (g,tid>>4) ------------
    const int pb = blockIdx.x * 32;
    const int p_cmb = tid >> 4;            // == 4w + q4
    const int g16 = tid & 15;
    f32x2 zc[2], ar[2];
    #pragma unroll
    for (int g = 0; g < 2; ++g) {
        int pl = pb + 16*g + p_cmb;
        int pg = (pl < B) ? pl : (B - 1);
        zc[g] = *(const f32x2*)&zin[pg*32 + 2*g16];
        *(f32x2*)&sZI[g][p_cmb*SZ_P + 2*g16] = zc[g];
    }
    __syncthreads();

    const float tv = tg[0];
    const int nst = nsg[0];
    const float dt = tv / (float)nst;

    const int xmask = (q4 >= 2) ? 0 : -1;

    #pragma unroll 1
    for (int st = 0; st < nst; ++st) {
        #pragma unroll 1
        for (int s = 0; s < 4; ++s) {
            float dreg[2][4];
            // ======== X-load + H, both sets ========
            #pragma unroll
            for (int g = 0; g < 2; ++g) {
                u16x8 xf;
                {
                    f32x4 xa = *(const f32x4*)&sZI[g][i16*SZ_P + 8*sc];
                    f32x4 xb = *(const f32x4*)&sZI[g][i16*SZ_P + 8*sc + 4];
                    xf.v2[0] = pk2(xa[0], xa[1]);
                    xf.v2[1] = pk2(xa[2], xa[3]);
                    xf.v2[2] = pk2(xb[0], xb[1]);
                    xf.v2[3] = pk2(xb[2], xb[3]);
                    #pragma unroll
                    for (int jp = 0; jp < 4; ++jp) xf.i32[jp] &= xmask;
                }
                f32x4 hc = {0.f, 0.f, 0.f, 0.f};
                hc = __builtin_amdgcn_mfma_f32_16x16x32_f16(w1h, xf.v8, hc, 0, 0, 0);
                float hv[4];
                #pragma unroll
                for (int reg = 0; reg < 4; ++reg) {
                    hv[reg] = fastTanh(hc[reg] + b1v[reg]);
                    dreg[g][reg] = hv[reg]*hv[reg] - 1.0f;
                }
                u16x4 hv4;
                hv4.v2[0] = pk2(hv[0], hv[1]);
                hv4.v2[1] = pk2(hv[2], hv[3]);
                *(f16x4*)&sHT[g][i16*SH_P + 16*w + 4*q4] = hv4.v4;
            }
            __syncthreads();   // B1: h ready
            // ======== A stage, both sets ========
            #pragma unroll
            for (int g = 0; g < 2; ++g) {
                f32x4 vA = *(const f32x4*)&sZI[g][i16*SZ_P + 16 + 4*w];
                f16x8 hf0 = *(const f16x8*)&sHT[g][i16*SH_P + 8*q4];
                f16x8 hf1 = *(const f16x8*)&sHT[g][i16*SH_P + 8*q4 + 32];
                float pw[4] = {0.f, 0.f, 0.f, 0.f};
                #pragma unroll
                for (int t = 0; t < 4; ++t) {
                    f32x4 ac = {0.f, 0.f, 0.f, 0.f};
                    ac = __builtin_amdgcn_mfma_f32_16x16x32_f16(w2a[t][0], hf0, ac, 0, 0, 0);
                    ac = __builtin_amdgcn_mfma_f32_16x16x32_f16(w2a[t][1], hf1, ac, 0, 0, 0);
                    float a0 = ac[0] + b2v[t][0], a1 = ac[1] + b2v[t][1];
                    float a2 = ac[2] + b2v[t][2], a3 = ac[3] + b2v[t][3];
                    float vv = vA[t];
                    pw[0] += vv * a0; pw[1] += vv * a1;
                    pw[2] += vv * a2; pw[3] += vv * a3;
                    u16x4 av;
                    av.v2[0] = pk2(a0, a1);
                    av.v2[1] = pk2(a2, a3);
                    *(f16x4*)&sAG[g][i16*SAG_P + 24*(4*w + t) + 4*q4] = av.v4;
                }
                f32x4 pwv = {pw[0], pw[1], pw[2], pw[3]};
                *(f32x4*)&sWp[g][(w*16 + i16)*SWP_C + 4*q4] = pwv;
            }
            __syncthreads();   // B2: A + w partials ready
            // ======== AAT (2 pair-MFMAs/wave/set) -> G^T over A region ========
            #pragma unroll
            for (int g = 0; g < 2; ++g) {
                #pragma unroll
                for (int u0 = 0; u0 < 2; ++u0) {
                    int u = 2*w + u0;
                    int pt = 2*u + sc;
                    f16x8 af = *(const f16x8*)&sAG[g][pt*SAG_P + 24*i16 + 8*h2];
                    f32x16 gz = {0.0f};
                    f32x16 gacc = __builtin_amdgcn_mfma_f32_32x32x16_f16(af, af, gz, 0, 0, 0);
                    float gv[8];
                    #pragma unroll
                    for (int rr = 0; rr < 4; ++rr) {
                        float lo0 = gacc[rr],     hi0 = gacc[rr + 8];
                        float lo1 = gacc[rr + 4], hi1 = gacc[rr + 12];
                        float g0 = sc ? hi0 : lo0;
                        float g1 = sc ? hi1 : lo1;
                        int a0 = 4*h2 + rr;
                        int a1 = 8 + 4*h2 + rr;
                        gv[rr]     = g0 + ((i16 == a0) ? 1.0f : 0.0f);
                        gv[4 + rr] = g1 + ((i16 == a1) ? 1.0f : 0.0f);
                    }
                    u16x4 g0p, g1p;
                    g0p.v2[0] = pk2(gv[0], gv[1]); g0p.v2[1] = pk2(gv[2], gv[3]);
                    g1p.v2[0] = pk2(gv[4], gv[5]); g1p.v2[1] = pk2(gv[6], gv[7]);
                    *(f16x4*)&sAG[g][pt*SAG_P + 24*i16 + 4*h2]     = g0p.v4;
                    *(f16x4*)&sAG[g][pt*SAG_P + 24*i16 + 8 + 4*h2] = g1p.v4;
                }
            }
            // ======== r stage, both sets ========
            #pragma unroll
            for (int g = 0; g < 2; ++g) {
                float vch[8];
                {
                    const float* vp = &sZI[g][i16*SZ_P + 16 + (q4 >> 1)];
                    #pragma unroll
                    for (int c = 0; c < 8; ++c) vch[c] = vp[2*c];
                }
                float wv[8];
                {
                    f32x4 s0 = *(const f32x4*)&sWp[g][(0*16 + i16)*SWP_C + 8*sc];
                    f32x4 s1 = *(const f32x4*)&sWp[g][(1*16 + i16)*SWP_C + 8*sc];
                    f32x4 s2 = *(const f32x4*)&sWp[g][(2*16 + i16)*SWP_C + 8*sc];
                    f32x4 s3 = *(const f32x4*)&sWp[g][(3*16 + i16)*SWP_C + 8*sc];
                    f32x4 t0 = *(const f32x4*)&sWp[g][(0*16 + i16)*SWP_C + 8*sc + 4];
                    f32x4 t1 = *(const f32x4*)&sWp[g][(1*16 + i16)*SWP_C + 8*sc + 4];
                    f32x4 t2 = *(const f32x4*)&sWp[g][(2*16 + i16)*SWP_C + 8*sc + 4];
                    f32x4 t3 = *(const f32x4*)&sWp[g][(3*16 + i16)*SWP_C + 8*sc + 4];
                    #pragma unroll
                    for (int j = 0; j < 4; ++j) {
                        wv[j]     = s0[j] + s1[j] + s2[j] + s3[j];
                        wv[4 + j] = t0[j] + t1[j] + t2[j] + t3[j];
                    }
                }
                f16x2 wfp[4];
                #pragma unroll
                for (int jp = 0; jp < 4; ++jp) wfp[jp] = pk2(wv[2*jp], wv[2*jp + 1]);
                f32x4 racc = {0.f, 0.f, 0.f, 0.f};
                #pragma unroll
                for (int ch = 0; ch < 8; ++ch) {
                    f16 vvh = (f16)vch[ch];
                    f16x2 vv2; vv2.x = vvh; vv2.y = vvh;
                    u16x8 uf;
                    #pragma unroll
                    for (int jp = 0; jp < 4; ++jp) uf.v2[jp] = vv2 * wfp[jp];
                    racc = __builtin_amdgcn_mfma_f32_16x16x32_f16(w2r[ch], uf.v8, racc, 0, 0, 0);
                }
                u16x4 tv4;
                tv4.v2[0] = pk2(dreg[g][0]*racc[0], dreg[g][1]*racc[1]);
                tv4.v2[1] = pk2(dreg[g][2]*racc[2], dreg[g][3]*racc[3]);
                *(f16x4*)&sHT[g][i16*SH_P + 16*w + 4*q4] = tv4.v4;   // t overwrites h
            }
            __syncthreads();   // B4: t ready (G/aug wave-private from here)
            // ======== q stage, both sets ========
            #pragma unroll
            for (int g = 0; g < 2; ++g) {
                int ptq = 4*w + (i16 & 3);
                f16x8 tb0 = *(const f16x8*)&sHT[g][ptq*SH_P + 8*q4];
                f16x8 tb1 = *(const f16x8*)&sHT[g][ptq*SH_P + 8*q4 + 32];
                f32x4 qa = {0.f, 0.f, 0.f, 0.f};
                qa = __builtin_amdgcn_mfma_f32_16x16x32_f16(w1q[0], tb0, qa, 0, 0, 0);
                qa = __builtin_amdgcn_mfma_f32_16x16x32_f16(w1q[1], tb1, qa, 0, 0, 0);
                if (i16 < 4) {
                    #pragma unroll
                    for (int reg = 0; reg < 4; ++reg)
                        sAG[g][(4*w + i16)*SAG_P + 24*(4*q4 + reg) + 16] = (f16)qa[reg];
                }
            }
            // ======== solve G y = aug; paired across sets (fe_all2) =========
            // setprio(1): this is the long dependent chain; favor it over the
            // other (desynced) block's slack-rich throughput VALU.
            {
                __builtin_amdgcn_s_setprio(1);
                const int psl = 4*w + q4;
                float R0[17], R1[17];
                {
                    const f16* rp0 = &sAG[0][psl*SAG_P + 24*i16];
                    const f16* rp1 = &sAG[1][psl*SAG_P + 24*i16];
                    f16x8 ra0 = *(const f16x8*)&rp0[0];
                    f16x8 rb0 = *(const f16x8*)&rp0[8];
                    f16x8 ra1 = *(const f16x8*)&rp1[0];
                    f16x8 rb1 = *(const f16x8*)&rp1[8];
                    #pragma unroll
                    for (int j = 0; j < 8; ++j) {
                        R0[j] = (float)ra0[j]; R0[8+j] = (float)rb0[j];
                        R1[j] = (float)ra1[j]; R1[8+j] = (float)rb1[j];
                    }
                    R0[16] = (float)rp0[16];
                    R1[16] = (float)rp1[16];
                }
                float inv0 = 1.0f, inv1 = 1.0f;
                fe_all2<0>(R0, R1, i16, inv0, inv1);
                sKV[0][psl*SW_P + i16] = R0[16] * inv0;
                sKV[1][psl*SW_P + i16] = R1[16] * inv1;
                __builtin_amdgcn_s_setprio(0);
            }
            // (no barrier: combine reads only this wave's points; DS in-order)
            // ======== RK4 combine, both sets ========
            #pragma unroll
            for (int g = 0; g < 2; ++g) {
                f32x2 kk;
                if (g16 < 8) kk = *(const f32x2*)&sZI[g][p_cmb*SZ_P + 16 + 2*g16];
                else         kk = *(const f32x2*)&sKV[g][p_cmb*SW_P + 2*(g16 - 8)];
                if (s == 0) ar[g] = kk;
                else {
                    float wgt = (s == 3) ? 1.0f : 2.0f;
                    ar[g].x += wgt * kk.x; ar[g].y += wgt * kk.y;
                }
                f32x2 zi;
                if (s < 3) {
                    float alpha = (s < 2) ? (0.5f * dt) : dt;
                    zi.x = zc[g].x + alpha * kk.x; zi.y = zc[g].y + alpha * kk.y;
                } else {
                    float c6 = dt / 6.0f;
                    zc[g].x += c6 * ar[g].x; zc[g].y += c6 * ar[g].y;
                    zi = zc[g];
                }
                *(f32x2*)&sZI[g][p_cmb*SZ_P + 2*g16] = zi;
            }
            __syncthreads();   // B6: zI ready for next eval
        }
    }
    #pragma unroll
    for (int g = 0; g < 2; ++g) {
        int pl = pb + 16*g + p_cmb;
        if (pl < B)
            *(f32x2*)&outg[pl*32 + 2*g16] = zc[g];
    }
}

extern "C" void kernel_launch(void* const* d_in, const int* in_sizes, int n_in,
                              void* d_out, int out_size, void* d_ws, size_t ws_size,
                              hipStream_t stream) {
    (void)n_in; (void)d_ws; (void)ws_size; (void)out_size;
    const float* z  = (const float*)d_in[0];
    const float* t  = (const float*)d_in[1];
    const float* W1 = (const float*)d_in[2];
    const float* b1 = (const float*)d_in[3];
    const float* W2 = (const float*)d_in[4];
    const float* b2 = (const float*)d_in[5];
    const int*   ns = (const int*)d_in[6];
    float* out = (float*)d_out;
    const int B = in_sizes[0] / 32;
    int grid = (B + 31) / 32;
    hipLaunchKernelGGL(geo_kernel, dim3(grid), dim3(256), 0, stream,
                       z, t, W1, b1, W2, b2, ns, out, B);
}